// Round 8
// baseline (13514.267 us; speedup 1.0000x reference)
//
#include <hip/hip_runtime.h>
#include <hip/hip_bf16.h>

#define B_ 256
#define T_ 512
#define D_ 256
#define H_ 1024
#define C_ 10

typedef __attribute__((ext_vector_type(8))) short short8;
typedef __attribute__((ext_vector_type(4))) float floatx4;

static __device__ __forceinline__ unsigned short f2bf(float f) {
    __hip_bfloat16 b = __float2bfloat16(f);
    return *reinterpret_cast<unsigned short*>(&b);
}
static __device__ __forceinline__ float bf2f(unsigned short u) {
    unsigned int v = ((unsigned int)u) << 16;
    return __uint_as_float(v);
}
static __device__ __forceinline__ float fast_tanh(float x) {
    float e = __expf(2.f * x);
    return 1.f - __fdividef(2.f, e + 1.f);
}

// ---------------------------------------------------------------------------
// Pack Wh gates into WhT[gate][j][k] = bf16(W_gate_h[k][j]) (transposed)
// ---------------------------------------------------------------------------
__global__ void lstm_pack_wht(const float* __restrict__ Wg,
                              const float* __restrict__ Wi,
                              const float* __restrict__ Wf,
                              const float* __restrict__ Wo,
                              unsigned short* __restrict__ WT) {
    __shared__ float tile[32][33];
    int g = blockIdx.z;
    const float* W = (g == 0) ? Wg : (g == 1) ? Wi : (g == 2) ? Wf : Wo;
    int j0 = blockIdx.x * 32;
    int k0 = blockIdx.y * 32;
    int tx = threadIdx.x & 31, ty = threadIdx.x >> 5;  // 32 x 8
    #pragma unroll
    for (int s = 0; s < 32; s += 8)
        tile[ty + s][tx] = W[(size_t)(k0 + ty + s) * H_ + j0 + tx];
    __syncthreads();
    unsigned short* out = WT + ((size_t)g << 20);
    #pragma unroll
    for (int s = 0; s < 32; s += 8)
        out[(size_t)(j0 + ty + s) * 1024 + k0 + tx] = f2bf(tile[tx][ty + s]);
}

// ---------------------------------------------------------------------------
// proj3[v][col] = sum_d emb[v][d] * Wx[d][col] + b[col], col in [0,4096)
// ---------------------------------------------------------------------------
__global__ void lstm_proj3(const float* __restrict__ emb,
                           const float* __restrict__ Wgx, const float* __restrict__ Wix,
                           const float* __restrict__ Wfx, const float* __restrict__ Wox,
                           const float* __restrict__ bg, const float* __restrict__ bi,
                           const float* __restrict__ bf_, const float* __restrict__ bo,
                           float* __restrict__ proj3) {
    int col = blockIdx.x * 256 + threadIdx.x;
    int v = blockIdx.y;
    int gate = col >> 10;
    int j = col & (H_ - 1);
    const float* Wx = (gate == 0) ? Wgx : (gate == 1) ? Wix : (gate == 2) ? Wfx : Wox;
    const float* bb = (gate == 0) ? bg : (gate == 1) ? bi : (gate == 2) ? bf_ : bo;
    float acc = bb[j];
    for (int d = 0; d < D_; ++d)
        acc += emb[v * D_ + d] * Wx[(size_t)d * H_ + j];
    proj3[(size_t)v * 4096 + col] = acc;
}

// ---------------------------------------------------------------------------
// Persistent LSTM recurrence — hierarchical-fence edition.
//
// Evidence base (r1-r7):
//  * fence pair (REL wbl2 + ACQ inv) is the ONLY proven mechanism that moves
//    plain-stored h across XCDs (r3 PASSED with it; r4-r7 without it all read
//    zero h — bitwise-identical failures).
//  * r3's cost was per-WG fences: 512 L2-walks/step ~= 20us. Here: ONE
//    release + ONE acquire per XCD per step (16 walks chip-wide).
//  * flag RMWs + atomic-load polls are globally visible (proven every round).
//
// Placement: HW_REG_XCC_ID (HW-verified) + per-XCD slot counter. 128KB LDS
// forces 1 WG/CU; cooperative launch forces all 256 resident -> exactly 32
// WGs per XCD. WG (xcd x, slot cw): rows x*32..+31, hcols cw*32..+31.
// Wave (s,ch) = 16-row slab x 16 hcols, all 4 gates in-lane -> in-register
// combine, no zbuf, no __syncthreads in the step loop.
//
// Per-step barrier:
//   every wave: stores -> vmcnt(0) -> RMW own flag slot
//   leader (cw==0, wave0): poll own XCD's 128 flags -> fence(REL) ->
//     RMW relq[t][x] -> poll relq[t][0..7] -> fence(ACQ) -> RMW rdy[t][x]
//   every wave at t+1: poll rdy[t][own xcd] (single broadcast address)
// ---------------------------------------------------------------------------
__launch_bounds__(256, 1)
__global__ void lstm_persist(const unsigned short* __restrict__ WhT,
                             const float* __restrict__ proj3,
                             const int* __restrict__ x,
                             unsigned short* __restrict__ hb0,
                             unsigned short* __restrict__ hb1,
                             int* __restrict__ wavefl,   // [T][8][32][4]
                             int* __restrict__ relq,     // [T][8]
                             int* __restrict__ rdy,      // [T][8]
                             int* __restrict__ xcdctr) { // [8]
    __shared__ unsigned short Blds[64 * 1024];  // 128 KB: gates 0,1 swizzled
    __shared__ float projL[3][128];
    __shared__ int s_place;

    const int tid = threadIdx.x;

    // ---- self-placement: XCD id + column slot ----
    {
        unsigned int xcc_raw;
        asm volatile("s_getreg_b32 %0, hwreg(HW_REG_XCC_ID)" : "=s"(xcc_raw));
        if (tid == 0) {
            int slot = atomicAdd(&xcdctr[xcc_raw & 7], 1);
            s_place = (int)((xcc_raw & 7) << 5) | (slot & 31);
        }
    }
    __syncthreads();
    const int xcc = s_place >> 5;   // 0..7  -> rows xcc*32..+31
    const int cw  = s_place & 31;   // 0..31 -> hcols cw*32..+31
    const int hc0 = cw * 32;

    // ---- one-time: LDS B for gates 0,1 (64 gate-cols x 1024 k, XOR swz) ----
    {
        const int q = tid & 63;            // g*32 + hcol_local
        const int g = q >> 5;
        const int j = hc0 + (q & 31);
        const int xq = (q & 7) << 3;
        const unsigned short* src = WhT + ((size_t)g << 20) + (size_t)j * 1024;
        const int kb0 = (tid >> 6) * 256;
        #pragma unroll
        for (int it = 0; it < 32; ++it) {
            int k = kb0 + 8 * it;
            *(short8*)(Blds + q * 1024 + (k ^ xq)) = *(const short8*)(src + k);
        }
    }
    for (int idx = tid; idx < 384; idx += 256) {
        int v = idx >> 7, q = idx & 127;
        projL[v][q] = proj3[(size_t)v * 4096 + (size_t)(q >> 5) * 1024 + hc0 + (q & 31)];
    }
    __syncthreads();

    // ---- wave/lane geometry ----
    const int w = tid >> 6;
    const int s = w >> 1;              // 16-row slab 0,1
    const int ch = w & 1;              // hcol-group 0,1
    const int lane = tid & 63;
    const int lr = lane & 15;
    const int kq = lane >> 4;          // 0..3
    const int R0 = xcc * 32 + 16 * s;
    const int hl = 16 * ch + lr;       // hcol_local 0..31
    const int xorq = (hl & 7) << 3;
    const size_t abase = (size_t)(R0 + lr) * H_ + 8 * kq;

    const unsigned short* BL0 = Blds + (size_t)hl * 1024;          // gate 0
    const unsigned short* BL1 = Blds + (size_t)(32 + hl) * 1024;   // gate 1
    const unsigned short* BG2 = WhT + ((size_t)2 << 20) + (size_t)(hc0 + hl) * 1024 + 8 * kq;
    const unsigned short* BG3 = WhT + ((size_t)3 << 20) + (size_t)(hc0 + hl) * 1024 + 8 * kq;

    const bool leader = (cw == 0) && (w == 0);

    float creg[4] = {0.f, 0.f, 0.f, 0.f};
    unsigned short* hbuf[2] = {hb0, hb1};

    union U4 { unsigned int u[4]; short8 v; };

    for (int t = 0; t < T_; ++t) {
        const unsigned short* h_in = hbuf[t & 1];
        unsigned short* h_out = hbuf[(t + 1) & 1];

        int tok[4];
        #pragma unroll
        for (int i = 0; i < 4; ++i)
            tok[i] = x[(size_t)(R0 + 4 * kq + i) * T_ + t];

        if (t > 0) {
            const int* rp = &rdy[(size_t)(t - 1) * 8 + xcc];
            while (__hip_atomic_load(rp, __ATOMIC_RELAXED,
                                     __HIP_MEMORY_SCOPE_AGENT) == 0) {}
            asm volatile("" ::: "memory");  // no hoisting of data loads
        }

        // ---- GEMM: z[16 rows x 4 gates x 16 hcols], K=1024 ----
        // A loads: 4B agent atomic loads (L1-bypass). Freshness is guaranteed
        // by the fence pair of step t-1, not by the load path.
        floatx4 acc[4] = {};
        #pragma unroll 4
        for (int k2 = 0; k2 < 32; ++k2) {
            U4 u;
            const unsigned int* ap = (const unsigned int*)(h_in + abase + 32 * k2);
            #pragma unroll
            for (int q4 = 0; q4 < 4; ++q4)
                u.u[q4] = __hip_atomic_load(ap + q4, __ATOMIC_RELAXED,
                                            __HIP_MEMORY_SCOPE_AGENT);
            short8 a = u.v;
            int ki = (32 * k2 + 8 * kq) ^ xorq;
            short8 b0 = *(const short8*)(BL0 + ki);
            short8 b1 = *(const short8*)(BL1 + ki);
            short8 b2 = *(const short8*)(BG2 + 32 * k2);
            short8 b3 = *(const short8*)(BG3 + 32 * k2);
            acc[0] = __builtin_amdgcn_mfma_f32_16x16x32_bf16(a, b0, acc[0], 0, 0, 0);
            acc[1] = __builtin_amdgcn_mfma_f32_16x16x32_bf16(a, b1, acc[1], 0, 0, 0);
            acc[2] = __builtin_amdgcn_mfma_f32_16x16x32_bf16(a, b2, acc[2], 0, 0, 0);
            acc[3] = __builtin_amdgcn_mfma_f32_16x16x32_bf16(a, b3, acc[3], 0, 0, 0);
        }

        // ---- in-register combine (all 4 gates in-lane); plain 2B stores ----
        #pragma unroll
        for (int i = 0; i < 4; ++i) {
            const float* pl = projL[tok[i]];
            float zg = fast_tanh(acc[0][i] + pl[hl]);
            float zi = fast_tanh(acc[1][i] + pl[32 + hl]);
            float zf = fast_tanh(acc[2][i] + pl[64 + hl]);
            float zo = fast_tanh(acc[3][i] + pl[96 + hl]);
            float cv = zg * zi + creg[i] * zf;
            creg[i] = cv;
            h_out[(size_t)(R0 + 4 * kq + i) * H_ + hc0 + hl] = f2bf(fast_tanh(cv) * zo);
        }

        if (t == T_ - 1) break;  // kernel-end implicit flush covers lstm_final

        // ---- per-step hierarchical barrier ----
        asm volatile("s_waitcnt vmcnt(0)" ::: "memory");  // stores in local L2
        if (lane == 0)
            __hip_atomic_exchange(&wavefl[(size_t)t * 1024 + xcc * 128 + cw * 4 + w],
                                  1, __ATOMIC_RELAXED, __HIP_MEMORY_SCOPE_AGENT);

        if (leader) {
            // wait for all 128 waves of THIS XCD
            const int* fb = wavefl + (size_t)t * 1024 + xcc * 128;
            while (true) {
                int v0 = __hip_atomic_load(&fb[lane], __ATOMIC_RELAXED,
                                           __HIP_MEMORY_SCOPE_AGENT);
                int v1 = __hip_atomic_load(&fb[64 + lane], __ATOMIC_RELAXED,
                                           __HIP_MEMORY_SCOPE_AGENT);
                if (__all(v0 != 0) && __all(v1 != 0)) break;
            }
            // ONE release per XCD: write back this XCD's dirty h lines
            __builtin_amdgcn_fence(__ATOMIC_RELEASE, "agent");
            if (lane == 0)
                __hip_atomic_exchange(&relq[(size_t)t * 8 + xcc], 1,
                                      __ATOMIC_RELAXED, __HIP_MEMORY_SCOPE_AGENT);
            // wait for all 8 XCDs' releases
            while (true) {
                int v = 1;
                if (lane < 8)
                    v = __hip_atomic_load(&relq[(size_t)t * 8 + lane],
                                          __ATOMIC_RELAXED, __HIP_MEMORY_SCOPE_AGENT);
                if (__all(v != 0)) break;
            }
            // ONE acquire per XCD: drop stale lines so L2 refills from LLC
            __builtin_amdgcn_fence(__ATOMIC_ACQUIRE, "agent");
            if (lane == 0)
                __hip_atomic_exchange(&rdy[(size_t)t * 8 + xcc], 1,
                                      __ATOMIC_RELAXED, __HIP_MEMORY_SCOPE_AGENT);
        }
    }
}

// ---------------------------------------------------------------------------
// Final projection + log_softmax. One block (64 threads) per batch row.
// ---------------------------------------------------------------------------
__global__ void lstm_final(const unsigned short* __restrict__ h,
                           const float* __restrict__ Wp,
                           const float* __restrict__ bp,
                           float* __restrict__ out) {
    int row = blockIdx.x;
    int lane = threadIdx.x;
    float acc[C_];
    #pragma unroll
    for (int cc = 0; cc < C_; ++cc) acc[cc] = 0.f;
    for (int k = lane; k < H_; k += 64) {
        float hv = bf2f(h[(size_t)row * H_ + k]);
        #pragma unroll
        for (int cc = 0; cc < C_; ++cc) acc[cc] += hv * Wp[(size_t)k * C_ + cc];
    }
    #pragma unroll
    for (int cc = 0; cc < C_; ++cc)
        #pragma unroll
        for (int off = 32; off > 0; off >>= 1)
            acc[cc] += __shfl_down(acc[cc], off);
    if (lane == 0) {
        float p[C_];
        float m = -1e30f;
        #pragma unroll
        for (int cc = 0; cc < C_; ++cc) {
            p[cc] = acc[cc] + bp[cc];
            m = fmaxf(m, p[cc]);
        }
        float se = 0.f;
        #pragma unroll
        for (int cc = 0; cc < C_; ++cc) se += expf(p[cc] - m);
        float lse = m + logf(se);
        #pragma unroll
        for (int cc = 0; cc < C_; ++cc) out[(size_t)row * C_ + cc] = p[cc] - lse;
    }
}

extern "C" void kernel_launch(void* const* d_in, const int* in_sizes, int n_in,
                              void* d_out, int out_size, void* d_ws, size_t ws_size,
                              hipStream_t stream) {
    const int* x = (const int*)d_in[0];
    const float* emb = (const float*)d_in[1];
    const float* W_gx = (const float*)d_in[2];
    const float* W_gh = (const float*)d_in[3];
    const float* b_g = (const float*)d_in[4];
    const float* W_ix = (const float*)d_in[5];
    const float* W_ih = (const float*)d_in[6];
    const float* b_i = (const float*)d_in[7];
    const float* W_fx = (const float*)d_in[8];
    const float* W_fh = (const float*)d_in[9];
    const float* b_f = (const float*)d_in[10];
    const float* W_ox = (const float*)d_in[11];
    const float* W_oh = (const float*)d_in[12];
    const float* b_o = (const float*)d_in[13];
    const float* W_ph = (const float*)d_in[14];
    const float* b_p = (const float*)d_in[15];
    float* out = (float*)d_out;

    // workspace layout
    char* ws = (char*)d_ws;
    unsigned short* WhT = (unsigned short*)ws;                   // 8 MB
    size_t off = (size_t)4 * 1024 * 1024 * 2;
    float* proj3 = (float*)(ws + off); off += 3 * 4096 * 4;      // 48 KB
    unsigned short* hbuf0 = (unsigned short*)(ws + off); off += (size_t)B_ * H_ * 2;
    unsigned short* hbuf1 = (unsigned short*)(ws + off); off += (size_t)B_ * H_ * 2;
    int* wavefl = (int*)(ws + off); off += (size_t)T_ * 1024 * 4;  // 2 MB
    int* relq = (int*)(ws + off); off += (size_t)T_ * 8 * 4;       // 16 KB
    int* rdy = (int*)(ws + off); off += (size_t)T_ * 8 * 4;        // 16 KB
    int* xcdctr = (int*)(ws + off); off += 8 * sizeof(int);

    // 1. pack WhT (bf16, transposed)
    lstm_pack_wht<<<dim3(32, 32, 4), 256, 0, stream>>>(W_gh, W_ih, W_fh, W_oh, WhT);
    // 2. proj3 = emb @ Wx + b
    lstm_proj3<<<dim3(16, 3), 256, 0, stream>>>(emb, W_gx, W_ix, W_fx, W_ox,
                                                b_g, b_i, b_f, b_o, proj3);
    // 3. zero h0, flags, counters (every launch -> replay-safe)
    hipMemsetAsync(hbuf0, 0, (size_t)B_ * H_ * 2, stream);
    hipMemsetAsync(wavefl, 0, (size_t)T_ * 1024 * 4, stream);
    hipMemsetAsync(relq, 0, (size_t)T_ * 8 * 4, stream);
    hipMemsetAsync(rdy, 0, (size_t)T_ * 8 * 4, stream);
    hipMemsetAsync(xcdctr, 0, 8 * sizeof(int), stream);

    // 4. persistent recurrence (cooperative: all 256 WGs co-resident)
    {
        const unsigned short* a0 = WhT;
        const float* a1 = proj3; const int* a2 = x;
        unsigned short* a3 = hbuf0; unsigned short* a4 = hbuf1;
        int* a5 = wavefl; int* a6 = relq; int* a7 = rdy; int* a8 = xcdctr;
        void* args[] = {&a0, &a1, &a2, &a3, &a4, &a5, &a6, &a7, &a8};
        hipLaunchCooperativeKernel((const void*)lstm_persist, dim3(256), dim3(256),
                                   args, 0, stream);
    }

    // 5. final projection + log_softmax (h_512 lands in hbuf0: T_ even)
    lstm_final<<<B_, 64, 0, stream>>>(hbuf0, W_ph, b_p, out);
}

// Round 9
// 10694.315 us; speedup vs baseline: 1.2637x; 1.2637x over previous
//
#include <hip/hip_runtime.h>
#include <hip/hip_bf16.h>

#define B_ 256
#define T_ 512
#define D_ 256
#define H_ 1024
#define C_ 10

typedef __attribute__((ext_vector_type(8))) short short8;
typedef __attribute__((ext_vector_type(4))) float floatx4;

static __device__ __forceinline__ unsigned short f2bf(float f) {
    __hip_bfloat16 b = __float2bfloat16(f);
    return *reinterpret_cast<unsigned short*>(&b);
}
static __device__ __forceinline__ float bf2f(unsigned short u) {
    unsigned int v = ((unsigned int)u) << 16;
    return __uint_as_float(v);
}
static __device__ __forceinline__ float fast_tanh(float x) {
    float e = __expf(2.f * x);
    return 1.f - __fdividef(2.f, e + 1.f);
}

// ---------------------------------------------------------------------------
// Pack Wh gates into WhT[gate][j][k] = bf16(W_gate_h[k][j]) (transposed)
// ---------------------------------------------------------------------------
__global__ void lstm_pack_wht(const float* __restrict__ Wg,
                              const float* __restrict__ Wi,
                              const float* __restrict__ Wf,
                              const float* __restrict__ Wo,
                              unsigned short* __restrict__ WT) {
    __shared__ float tile[32][33];
    int g = blockIdx.z;
    const float* W = (g == 0) ? Wg : (g == 1) ? Wi : (g == 2) ? Wf : Wo;
    int j0 = blockIdx.x * 32;
    int k0 = blockIdx.y * 32;
    int tx = threadIdx.x & 31, ty = threadIdx.x >> 5;  // 32 x 8
    #pragma unroll
    for (int s = 0; s < 32; s += 8)
        tile[ty + s][tx] = W[(size_t)(k0 + ty + s) * H_ + j0 + tx];
    __syncthreads();
    unsigned short* out = WT + ((size_t)g << 20);
    #pragma unroll
    for (int s = 0; s < 32; s += 8)
        out[(size_t)(j0 + ty + s) * 1024 + k0 + tx] = f2bf(tile[tx][ty + s]);
}

// ---------------------------------------------------------------------------
// proj3[v][col] = sum_d emb[v][d] * Wx[d][col] + b[col], col in [0,4096)
// ---------------------------------------------------------------------------
__global__ void lstm_proj3(const float* __restrict__ emb,
                           const float* __restrict__ Wgx, const float* __restrict__ Wix,
                           const float* __restrict__ Wfx, const float* __restrict__ Wox,
                           const float* __restrict__ bg, const float* __restrict__ bi,
                           const float* __restrict__ bf_, const float* __restrict__ bo,
                           float* __restrict__ proj3) {
    int col = blockIdx.x * 256 + threadIdx.x;
    int v = blockIdx.y;
    int gate = col >> 10;
    int j = col & (H_ - 1);
    const float* Wx = (gate == 0) ? Wgx : (gate == 1) ? Wix : (gate == 2) ? Wfx : Wox;
    const float* bb = (gate == 0) ? bg : (gate == 1) ? bi : (gate == 2) ? bf_ : bo;
    float acc = bb[j];
    for (int d = 0; d < D_; ++d)
        acc += emb[v * D_ + d] * Wx[(size_t)d * H_ + j];
    proj3[(size_t)v * 4096 + col] = acc;
}

// ---------------------------------------------------------------------------
// Persistent LSTM recurrence — flat single-level barrier edition.
//
// Evidence base (r1-r8):
//  * The ONLY proven h-exchange recipe: plain stores -> vmcnt drain ->
//    fence(REL,agent) -> flag RMW ; poll flags -> fence(ACQ,agent) -> plain
//    loads. (r3, r8 passed with it; r4-r7 without fences all read zero h.)
//  * Fence COUNT is irrelevant: r3 (512/step) ~= r8 (16/step) ~= 23-26us/step
//    -> the wall is the SERIALIZED SYNC-CHAIN LATENCY (r8: ~5 LLC RTs via a
//    2-level leader chain) + poll-storm congestion + ACQ-inv evicting the
//    streamed B gates every step (r8: 2.3 GB HBM refetch).
//
// This round:
//  * WG = 64 rows x 16 hcols (64 gate-cols): ALL 4 gates in 128 KB LDS ->
//    zero streamed B -> ACQ-inv has nothing valuable to evict.
//  * Row-block = 64 WGs covering 64 rows x 1024 hcols. Single-level barrier:
//    each WG sets one flag slot (16B-strided to avoid RMW line serialization)
//    and polls all 64 slots of its row-block directly (one per lane).
//    Chain: flag RMW -> poll -> ACQ -> loads  (~3 RTs, no leaders).
//  * s_sleep(1) backoff in polls to cut fabric congestion.
//  * Wave = 16-row slab, all 4 gates in-lane -> in-register combine, no zbuf.
//  * WAR-safe: a WG flags step t only after its step-t reads (registers) and
//    stores; it may store into hbuf[t&1] at step t+1 only after all 64 flags
//    of step t -> all step-t reads of that buffer are complete.
// ---------------------------------------------------------------------------
__launch_bounds__(256, 1)
__global__ void lstm_persist(const unsigned short* __restrict__ WhT,
                             const float* __restrict__ proj3,
                             const int* __restrict__ x,
                             unsigned short* __restrict__ hb0,
                             unsigned short* __restrict__ hb1,
                             int* __restrict__ flg) {   // [T][4][64 slots x4]
    __shared__ unsigned short Blds[64 * 1024];  // 128 KB: 4 gates x 16 hcols
    __shared__ float projL[3][64];              // [vocab][g*16+hcol_local]

    const int bid = blockIdx.x;
    const int rb = bid >> 6;        // 0..3 row-block (64 rows)
    const int cw = bid & 63;        // 0..63 col slot (16 hcols)
    const int r0 = rb * 64;
    const int hc0 = cw * 16;
    const int tid = threadIdx.x;

    // ---- one-time: LDS B, 64 gate-cols x 1024 k, XOR-swizzled ----
    {
        const int q = tid & 63;            // g*16 + hcol_local
        const int g = q >> 4;
        const int j = hc0 + (q & 15);
        const int xq = (q & 7) << 3;
        const unsigned short* src = WhT + ((size_t)g << 20) + (size_t)j * 1024;
        const int kb0 = (tid >> 6) * 256;
        #pragma unroll
        for (int it = 0; it < 32; ++it) {
            int k = kb0 + 8 * it;
            *(short8*)(Blds + q * 1024 + (k ^ xq)) = *(const short8*)(src + k);
        }
    }
    for (int idx = tid; idx < 192; idx += 256) {
        int v = idx >> 6, q = idx & 63;
        projL[v][q] = proj3[(size_t)v * 4096 + (size_t)(q >> 4) * 1024 + hc0 + (q & 15)];
    }
    __syncthreads();

    // ---- wave/lane geometry: wave w = 16-row slab, all 64 gate-cols ----
    const int w = tid >> 6;
    const int lane = tid & 63;
    const int lr = lane & 15;
    const int kq = lane >> 4;          // 0..3
    const int arow = r0 + 16 * w + lr;               // A-operand row
    const size_t abase = (size_t)arow * H_ + 8 * kq;
    const int crow0 = r0 + 16 * w + 4 * kq;          // C rows +i
    const int xorq = (lr & 7) << 3;

    const unsigned short* B0 = Blds + (size_t)(lr) * 1024;        // gate 0
    const unsigned short* B1 = Blds + (size_t)(16 + lr) * 1024;   // gate 1
    const unsigned short* B2 = Blds + (size_t)(32 + lr) * 1024;   // gate 2
    const unsigned short* B3 = Blds + (size_t)(48 + lr) * 1024;   // gate 3

    float creg[4] = {0.f, 0.f, 0.f, 0.f};
    unsigned short* hbuf[2] = {hb0, hb1};

    for (int t = 0; t < T_; ++t) {
        const unsigned short* h_in = hbuf[t & 1];
        unsigned short* h_out = hbuf[(t + 1) & 1];

        // tokens: immutable input (stale cache lines are still correct)
        int tok[4];
        #pragma unroll
        for (int i = 0; i < 4; ++i)
            tok[i] = x[(size_t)(crow0 + i) * T_ + t];

        if (t > 0) {
            // poll the 64 WG-flags of this row-block (1 slot/lane, 16B stride)
            const int* fa = flg + ((size_t)(t - 1) * 4 + rb) * 256;
            while (true) {
                int v = __hip_atomic_load(&fa[lane * 4], __ATOMIC_RELAXED,
                                          __HIP_MEMORY_SCOPE_AGENT);
                if (__all(v != 0)) break;
                __builtin_amdgcn_s_sleep(1);   // backoff: cut poll-storm congestion
            }
            __builtin_amdgcn_fence(__ATOMIC_ACQUIRE, "agent");  // drop stale h lines
        }

        // ---- GEMM: z[16 rows x 64 gate-cols], K=1024; plain loads ----
        floatx4 acc[4] = {};
        #pragma unroll 8
        for (int k2 = 0; k2 < 32; ++k2) {
            short8 a = *(const short8*)(h_in + abase + 32 * k2);
            int ki = (32 * k2 + 8 * kq) ^ xorq;
            short8 b0 = *(const short8*)(B0 + ki);
            short8 b1 = *(const short8*)(B1 + ki);
            short8 b2 = *(const short8*)(B2 + ki);
            short8 b3 = *(const short8*)(B3 + ki);
            acc[0] = __builtin_amdgcn_mfma_f32_16x16x32_bf16(a, b0, acc[0], 0, 0, 0);
            acc[1] = __builtin_amdgcn_mfma_f32_16x16x32_bf16(a, b1, acc[1], 0, 0, 0);
            acc[2] = __builtin_amdgcn_mfma_f32_16x16x32_bf16(a, b2, acc[2], 0, 0, 0);
            acc[3] = __builtin_amdgcn_mfma_f32_16x16x32_bf16(a, b3, acc[3], 0, 0, 0);
        }

        // ---- in-register combine (all 4 gates in-lane); plain 2B stores ----
        #pragma unroll
        for (int i = 0; i < 4; ++i) {
            const float* pl = projL[tok[i]];
            float zg = fast_tanh(acc[0][i] + pl[lr]);
            float zi = fast_tanh(acc[1][i] + pl[16 + lr]);
            float zf = fast_tanh(acc[2][i] + pl[32 + lr]);
            float zo = fast_tanh(acc[3][i] + pl[48 + lr]);
            float cv = zg * zi + creg[i] * zf;
            creg[i] = cv;
            h_out[(size_t)(crow0 + i) * H_ + hc0 + lr] = f2bf(fast_tanh(cv) * zo);
        }

        if (t == T_ - 1) break;  // kernel-end release flushes for lstm_final

        // ---- release: all waves' stores in L2 -> one wbl2 -> flag ----
        __syncthreads();  // compiler drains vmcnt before s_barrier
        if (tid == 0) {
            __builtin_amdgcn_fence(__ATOMIC_RELEASE, "agent");
            __hip_atomic_exchange(
                flg + (((size_t)t * 4 + rb) * 64 + cw) * 4, 1,
                __ATOMIC_RELAXED, __HIP_MEMORY_SCOPE_AGENT);
        }
    }
}

// ---------------------------------------------------------------------------
// Final projection + log_softmax. One block (64 threads) per batch row.
// ---------------------------------------------------------------------------
__global__ void lstm_final(const unsigned short* __restrict__ h,
                           const float* __restrict__ Wp,
                           const float* __restrict__ bp,
                           float* __restrict__ out) {
    int row = blockIdx.x;
    int lane = threadIdx.x;
    float acc[C_];
    #pragma unroll
    for (int cc = 0; cc < C_; ++cc) acc[cc] = 0.f;
    for (int k = lane; k < H_; k += 64) {
        float hv = bf2f(h[(size_t)row * H_ + k]);
        #pragma unroll
        for (int cc = 0; cc < C_; ++cc) acc[cc] += hv * Wp[(size_t)k * C_ + cc];
    }
    #pragma unroll
    for (int cc = 0; cc < C_; ++cc)
        #pragma unroll
        for (int off = 32; off > 0; off >>= 1)
            acc[cc] += __shfl_down(acc[cc], off);
    if (lane == 0) {
        float p[C_];
        float m = -1e30f;
        #pragma unroll
        for (int cc = 0; cc < C_; ++cc) {
            p[cc] = acc[cc] + bp[cc];
            m = fmaxf(m, p[cc]);
        }
        float se = 0.f;
        #pragma unroll
        for (int cc = 0; cc < C_; ++cc) se += expf(p[cc] - m);
        float lse = m + logf(se);
        #pragma unroll
        for (int cc = 0; cc < C_; ++cc) out[(size_t)row * C_ + cc] = p[cc] - lse;
    }
}

extern "C" void kernel_launch(void* const* d_in, const int* in_sizes, int n_in,
                              void* d_out, int out_size, void* d_ws, size_t ws_size,
                              hipStream_t stream) {
    const int* x = (const int*)d_in[0];
    const float* emb = (const float*)d_in[1];
    const float* W_gx = (const float*)d_in[2];
    const float* W_gh = (const float*)d_in[3];
    const float* b_g = (const float*)d_in[4];
    const float* W_ix = (const float*)d_in[5];
    const float* W_ih = (const float*)d_in[6];
    const float* b_i = (const float*)d_in[7];
    const float* W_fx = (const float*)d_in[8];
    const float* W_fh = (const float*)d_in[9];
    const float* b_f = (const float*)d_in[10];
    const float* W_ox = (const float*)d_in[11];
    const float* W_oh = (const float*)d_in[12];
    const float* b_o = (const float*)d_in[13];
    const float* W_ph = (const float*)d_in[14];
    const float* b_p = (const float*)d_in[15];
    float* out = (float*)d_out;

    // workspace layout
    char* ws = (char*)d_ws;
    unsigned short* WhT = (unsigned short*)ws;                   // 8 MB
    size_t off = (size_t)4 * 1024 * 1024 * 2;
    float* proj3 = (float*)(ws + off); off += 3 * 4096 * 4;      // 48 KB
    unsigned short* hbuf0 = (unsigned short*)(ws + off); off += (size_t)B_ * H_ * 2;
    unsigned short* hbuf1 = (unsigned short*)(ws + off); off += (size_t)B_ * H_ * 2;
    int* flg = (int*)(ws + off); off += (size_t)T_ * 4 * 64 * 4 * 4;  // 2 MB

    // 1. pack WhT (bf16, transposed)
    lstm_pack_wht<<<dim3(32, 32, 4), 256, 0, stream>>>(W_gh, W_ih, W_fh, W_oh, WhT);
    // 2. proj3 = emb @ Wx + b
    lstm_proj3<<<dim3(16, 3), 256, 0, stream>>>(emb, W_gx, W_ix, W_fx, W_ox,
                                                b_g, b_i, b_f, b_o, proj3);
    // 3. zero h0 and flags (every launch -> replay-safe)
    hipMemsetAsync(hbuf0, 0, (size_t)B_ * H_ * 2, stream);
    hipMemsetAsync(flg, 0, (size_t)T_ * 4 * 64 * 4 * 4, stream);

    // 4. persistent recurrence (cooperative: all 256 WGs co-resident)
    {
        const unsigned short* a0 = WhT;
        const float* a1 = proj3; const int* a2 = x;
        unsigned short* a3 = hbuf0; unsigned short* a4 = hbuf1;
        int* a5 = flg;
        void* args[] = {&a0, &a1, &a2, &a3, &a4, &a5};
        hipLaunchCooperativeKernel((const void*)lstm_persist, dim3(256), dim3(256),
                                   args, 0, stream);
    }

    // 5. final projection + log_softmax (h_512 lands in hbuf0: T_ even)
    lstm_final<<<B_, 64, 0, stream>>>(hbuf0, W_ph, b_p, out);
}